// Round 1
// baseline (762.367 us; speedup 1.0000x reference)
//
#include <hip/hip_runtime.h>
#include <math.h>

#define NB 4096            // batch
#define DIMX 784           // feature dim for x / y pdists

__device__ __forceinline__ float lrelu_f(float v) { return v >= 0.f ? v : 0.01f * v; }

// ---------------------------------------------------------------------------
// Generic tiled fp32 GEMM: C[M,N] = act(A[M,K] @ W[N,K]^T + bias[N])
// ACT: 0 = none, 1 = leaky_relu, 2 = sigmoid, 3 = tanh(leaky_relu(.))
// 64x64 tile, BK=16, 256 threads, 4x4 microtile per thread.
// ---------------------------------------------------------------------------
template<int ACT>
__global__ __launch_bounds__(256) void gemm_bias_act(
    const float* __restrict__ A, const float* __restrict__ W,
    const float* __restrict__ bias, float* __restrict__ C,
    int M, int N, int K)
{
    __shared__ float As[16][64];
    __shared__ float Bs[16][64];
    const int tid = threadIdx.x;
    const int tx = tid & 15, ty = tid >> 4;
    const int m0 = blockIdx.y * 64, n0 = blockIdx.x * 64;
    const int q = tid & 3, lr = tid >> 2;   // loader: row lr (0..63), k-quad q

    float acc[4][4] = {};

    for (int kt = 0; kt < K; kt += 16) {
        const int gk = kt + 4 * q;
        // ---- A tile ----
        {
            const int gm = m0 + lr;
            float4 v = {0.f, 0.f, 0.f, 0.f};
            if (gm < M) {
                if (((K & 3) == 0) && (gk + 3 < K)) {
                    v = *(const float4*)(A + (size_t)gm * K + gk);
                } else {
                    const float* p = A + (size_t)gm * K;
                    if (gk     < K) v.x = p[gk];
                    if (gk + 1 < K) v.y = p[gk + 1];
                    if (gk + 2 < K) v.z = p[gk + 2];
                    if (gk + 3 < K) v.w = p[gk + 3];
                }
            }
            As[4*q+0][lr] = v.x; As[4*q+1][lr] = v.y;
            As[4*q+2][lr] = v.z; As[4*q+3][lr] = v.w;
        }
        // ---- W tile ----
        {
            const int gn = n0 + lr;
            float4 v = {0.f, 0.f, 0.f, 0.f};
            if (gn < N) {
                if (((K & 3) == 0) && (gk + 3 < K)) {
                    v = *(const float4*)(W + (size_t)gn * K + gk);
                } else {
                    const float* p = W + (size_t)gn * K;
                    if (gk     < K) v.x = p[gk];
                    if (gk + 1 < K) v.y = p[gk + 1];
                    if (gk + 2 < K) v.z = p[gk + 2];
                    if (gk + 3 < K) v.w = p[gk + 3];
                }
            }
            Bs[4*q+0][lr] = v.x; Bs[4*q+1][lr] = v.y;
            Bs[4*q+2][lr] = v.z; Bs[4*q+3][lr] = v.w;
        }
        __syncthreads();
        #pragma unroll
        for (int kk = 0; kk < 16; ++kk) {
            float4 a = *(const float4*)&As[kk][ty * 4];
            float4 b = *(const float4*)&Bs[kk][tx * 4];
            float av[4] = {a.x, a.y, a.z, a.w};
            float bv[4] = {b.x, b.y, b.z, b.w};
            #pragma unroll
            for (int i = 0; i < 4; ++i)
                #pragma unroll
                for (int j = 0; j < 4; ++j)
                    acc[i][j] = fmaf(av[i], bv[j], acc[i][j]);
        }
        __syncthreads();
    }

    #pragma unroll
    for (int i = 0; i < 4; ++i) {
        const int gm = m0 + ty * 4 + i;
        if (gm >= M) continue;
        #pragma unroll
        for (int j = 0; j < 4; ++j) {
            const int gn = n0 + tx * 4 + j;
            if (gn >= N) continue;
            float v = acc[i][j] + bias[gn];
            if (ACT == 1)      v = lrelu_f(v);
            else if (ACT == 2) v = 1.f / (1.f + expf(-v));
            else if (ACT == 3) v = tanhf(lrelu_f(v));
            C[(size_t)gm * N + gn] = v;
        }
    }
}

// ---------------------------------------------------------------------------
// Row squared-norms: sq[r] = sum_k X[r,k]^2   (one block per row)
// ---------------------------------------------------------------------------
__global__ __launch_bounds__(256) void rowsq_kernel(
    const float* __restrict__ X, float* __restrict__ sq, int K)
{
    const int r = blockIdx.x;
    const int tid = threadIdx.x;
    float s = 0.f;
    const float* row = X + (size_t)r * K;
    for (int k = tid; k < K; k += 256) { float v = row[k]; s = fmaf(v, v, s); }
    __shared__ float red[256];
    red[tid] = s;
    __syncthreads();
    for (int off = 128; off > 0; off >>= 1) {
        if (tid < off) red[tid] += red[tid + off];
        __syncthreads();
    }
    if (tid == 0) sq[r] = red[0];
}

// ---------------------------------------------------------------------------
// pdist via Gram trick, upper-triangle tiles only.
// out[pairIdx(i,j)] = sqrt(max(sq[i]+sq[j]-2*dot(x_i,x_j), 0)) for i<j.
// ---------------------------------------------------------------------------
__global__ __launch_bounds__(256) void pdist_gram(
    const float* __restrict__ X, const float* __restrict__ sq,
    float* __restrict__ out)
{
    const int ti = blockIdx.y, tj = blockIdx.x;
    if (ti > tj) return;               // lower-triangle tiles: nothing to do
    __shared__ float As[16][64];
    __shared__ float Bs[16][64];
    const int tid = threadIdx.x;
    const int tx = tid & 15, ty = tid >> 4;
    const int i0 = ti * 64, j0 = tj * 64;
    const int q = tid & 3, lr = tid >> 2;

    float acc[4][4] = {};

    for (int kt = 0; kt < DIMX; kt += 16) {
        const int gk = kt + 4 * q;
        float4 a = *(const float4*)(X + (size_t)(i0 + lr) * DIMX + gk);
        float4 b = *(const float4*)(X + (size_t)(j0 + lr) * DIMX + gk);
        As[4*q+0][lr] = a.x; As[4*q+1][lr] = a.y;
        As[4*q+2][lr] = a.z; As[4*q+3][lr] = a.w;
        Bs[4*q+0][lr] = b.x; Bs[4*q+1][lr] = b.y;
        Bs[4*q+2][lr] = b.z; Bs[4*q+3][lr] = b.w;
        __syncthreads();
        #pragma unroll
        for (int kk = 0; kk < 16; ++kk) {
            float4 av4 = *(const float4*)&As[kk][ty * 4];
            float4 bv4 = *(const float4*)&Bs[kk][tx * 4];
            float av[4] = {av4.x, av4.y, av4.z, av4.w};
            float bv[4] = {bv4.x, bv4.y, bv4.z, bv4.w};
            #pragma unroll
            for (int i = 0; i < 4; ++i)
                #pragma unroll
                for (int j = 0; j < 4; ++j)
                    acc[i][j] = fmaf(av[i], bv[j], acc[i][j]);
        }
        __syncthreads();
    }

    float sqi[4], sqj[4];
    #pragma unroll
    for (int i = 0; i < 4; ++i) sqi[i] = sq[i0 + ty * 4 + i];
    #pragma unroll
    for (int j = 0; j < 4; ++j) sqj[j] = sq[j0 + tx * 4 + j];

    #pragma unroll
    for (int i = 0; i < 4; ++i) {
        const int gi = i0 + ty * 4 + i;
        #pragma unroll
        for (int j = 0; j < 4; ++j) {
            const int gj = j0 + tx * 4 + j;
            if (gj > gi) {
                float d2 = sqi[i] + sqj[j] - 2.f * acc[i][j];
                int idx = (gi * (2 * NB - 1 - gi)) / 2 + (gj - gi - 1);
                out[idx] = sqrtf(fmaxf(d2, 0.f));
            }
        }
    }
}

// ---------------------------------------------------------------------------
// pdist for 2-D latent z, direct difference formula (no cancellation).
// ---------------------------------------------------------------------------
__global__ __launch_bounds__(256) void pdist_z(
    const float* __restrict__ Z, float* __restrict__ out)
{
    const int ti = blockIdx.y, tj = blockIdx.x;
    if (ti > tj) return;
    __shared__ float zi[64][2];
    __shared__ float zj[64][2];
    const int tid = threadIdx.x;
    if (tid < 128) {
        int r = tid >> 1, c = tid & 1;
        zi[r][c] = Z[(size_t)(ti * 64 + r) * 2 + c];
        zj[r][c] = Z[(size_t)(tj * 64 + r) * 2 + c];
    }
    __syncthreads();
    const int tx = tid & 15, ty = tid >> 4;
    #pragma unroll
    for (int i = 0; i < 4; ++i) {
        const int li = ty * 4 + i;
        const int gi = ti * 64 + li;
        #pragma unroll
        for (int j = 0; j < 4; ++j) {
            const int lj = tx * 4 + j;
            const int gj = tj * 64 + lj;
            if (gj > gi) {
                float d0 = zi[li][0] - zj[lj][0];
                float d1 = zi[li][1] - zj[lj][1];
                int idx = (gi * (2 * NB - 1 - gi)) / 2 + (gj - gi - 1);
                out[idx] = sqrtf(fmaf(d0, d0, d1 * d1));
            }
        }
    }
}

// ---------------------------------------------------------------------------
extern "C" void kernel_launch(void* const* d_in, const int* in_sizes, int n_in,
                              void* d_out, int out_size, void* d_ws, size_t ws_size,
                              hipStream_t stream)
{
    const float* x       = (const float*)d_in[0];   // [4096,784] (flattened 1x28x28)
    const float* fc1_w   = (const float*)d_in[1];
    const float* fc1_b   = (const float*)d_in[2];
    const float* fc11_w  = (const float*)d_in[3];
    const float* fc11_b  = (const float*)d_in[4];
    const float* fc12_w  = (const float*)d_in[5];
    const float* fc12_b  = (const float*)d_in[6];
    const float* fc2_w   = (const float*)d_in[7];
    const float* fc2_b   = (const float*)d_in[8];
    const float* fc3_w   = (const float*)d_in[9];
    const float* fc3_b   = (const float*)d_in[10];
    const float* fc31_w  = (const float*)d_in[11];
    const float* fc31_b  = (const float*)d_in[12];
    const float* fc32_w  = (const float*)d_in[13];
    const float* fc32_b  = (const float*)d_in[14];
    const float* fc4_w   = (const float*)d_in[15];
    const float* fc4_b   = (const float*)d_in[16];

    float* out = (float*)d_out;
    // output layout (flat, return order)
    const size_t Y_OFF   = 0;                       // 4096*784
    const size_t IN_OFF  = 3211264;                 // 8386560
    const size_t LAT_OFF = 11597824;                // 8386560
    const size_t OUT_OFF = 19984384;                // 8386560
    const size_t Z_OFF   = 28370944;                // 4096*2

    float* y        = out + Y_OFF;
    float* in_diff  = out + IN_OFF;
    float* lat_diff = out + LAT_OFF;
    float* out_diff = out + OUT_OFF;
    float* z        = out + Z_OFF;

    // workspace layout (floats)
    float* ws  = (float*)d_ws;
    float* h1  = ws;                      // 4096*400
    float* h2  = h1 + (size_t)4096 * 400; // 4096*200
    float* h3  = h2 + (size_t)4096 * 200; // 4096*50   (tanh(lrelu(.)) applied)
    float* y1  = h3 + (size_t)4096 * 50;  // 4096*50
    float* y2  = y1 + (size_t)4096 * 50;  // 4096*200
    float* y3  = y2 + (size_t)4096 * 200; // 4096*400
    float* sqx = y3 + (size_t)4096 * 400; // 4096
    float* sqy = sqx + 4096;              // 4096

    const dim3 blk(256);
    auto grd = [](int M, int N) { return dim3((N + 63) / 64, (M + 63) / 64); };

    // encoder
    gemm_bias_act<1><<<grd(NB, 400), blk, 0, stream>>>(x,  fc1_w,  fc1_b,  h1, NB, 400, 784);
    gemm_bias_act<1><<<grd(NB, 200), blk, 0, stream>>>(h1, fc11_w, fc11_b, h2, NB, 200, 400);
    gemm_bias_act<3><<<grd(NB,  50), blk, 0, stream>>>(h2, fc12_w, fc12_b, h3, NB,  50, 200); // tanh(lrelu)
    gemm_bias_act<0><<<grd(NB,   2), blk, 0, stream>>>(h3, fc2_w,  fc2_b,  z,  NB,   2,  50);
    // decoder
    gemm_bias_act<1><<<grd(NB,  50), blk, 0, stream>>>(z,  fc3_w,  fc3_b,  y1, NB,  50,   2);
    gemm_bias_act<1><<<grd(NB, 200), blk, 0, stream>>>(y1, fc31_w, fc31_b, y2, NB, 200,  50);
    gemm_bias_act<1><<<grd(NB, 400), blk, 0, stream>>>(y2, fc32_w, fc32_b, y3, NB, 400, 200);
    gemm_bias_act<2><<<grd(NB, 784), blk, 0, stream>>>(y3, fc4_w,  fc4_b,  y,  NB, 784, 400); // sigmoid

    // squared norms
    rowsq_kernel<<<dim3(NB), blk, 0, stream>>>(x, sqx, DIMX);
    rowsq_kernel<<<dim3(NB), blk, 0, stream>>>(y, sqy, DIMX);

    // pairwise distances
    pdist_gram<<<dim3(64, 64), blk, 0, stream>>>(x, sqx, in_diff);
    pdist_gram<<<dim3(64, 64), blk, 0, stream>>>(y, sqy, out_diff);
    pdist_z  <<<dim3(64, 64), blk, 0, stream>>>(z, lat_diff);
}

// Round 3
// 538.061 us; speedup vs baseline: 1.4169x; 1.4169x over previous
//
#include <hip/hip_runtime.h>
#include <math.h>

#define NB 4096            // batch
#define DIMX 784           // feature dim for x / y pdists
#define SEG 800            // padded segment length (25*32)
#define RS 1600            // row stride in shorts: [hi(800) | lo(800)]

typedef __attribute__((ext_vector_type(8))) short bf16x8;
typedef __attribute__((ext_vector_type(4))) float f32x4;

__device__ __forceinline__ float lrelu_f(float v) { return v >= 0.f ? v : 0.01f * v; }

// ---------------------------------------------------------------------------
// Generic tiled fp32 GEMM: C[M,N] = act(A[M,K] @ W[N,K]^T + bias[N])
// ACT: 0 = none, 1 = leaky_relu, 2 = sigmoid, 3 = tanh(leaky_relu(.))
// ---------------------------------------------------------------------------
template<int ACT>
__global__ __launch_bounds__(256) void gemm_bias_act(
    const float* __restrict__ A, const float* __restrict__ W,
    const float* __restrict__ bias, float* __restrict__ C,
    int M, int N, int K)
{
    __shared__ float As[16][64];
    __shared__ float Bs[16][64];
    const int tid = threadIdx.x;
    const int tx = tid & 15, ty = tid >> 4;
    const int m0 = blockIdx.y * 64, n0 = blockIdx.x * 64;
    const int q = tid & 3, lr = tid >> 2;

    float acc[4][4] = {};

    for (int kt = 0; kt < K; kt += 16) {
        const int gk = kt + 4 * q;
        {
            const int gm = m0 + lr;
            float4 v = {0.f, 0.f, 0.f, 0.f};
            if (gm < M) {
                if (((K & 3) == 0) && (gk + 3 < K)) {
                    v = *(const float4*)(A + (size_t)gm * K + gk);
                } else {
                    const float* p = A + (size_t)gm * K;
                    if (gk     < K) v.x = p[gk];
                    if (gk + 1 < K) v.y = p[gk + 1];
                    if (gk + 2 < K) v.z = p[gk + 2];
                    if (gk + 3 < K) v.w = p[gk + 3];
                }
            }
            As[4*q+0][lr] = v.x; As[4*q+1][lr] = v.y;
            As[4*q+2][lr] = v.z; As[4*q+3][lr] = v.w;
        }
        {
            const int gn = n0 + lr;
            float4 v = {0.f, 0.f, 0.f, 0.f};
            if (gn < N) {
                if (((K & 3) == 0) && (gk + 3 < K)) {
                    v = *(const float4*)(W + (size_t)gn * K + gk);
                } else {
                    const float* p = W + (size_t)gn * K;
                    if (gk     < K) v.x = p[gk];
                    if (gk + 1 < K) v.y = p[gk + 1];
                    if (gk + 2 < K) v.z = p[gk + 2];
                    if (gk + 3 < K) v.w = p[gk + 3];
                }
            }
            Bs[4*q+0][lr] = v.x; Bs[4*q+1][lr] = v.y;
            Bs[4*q+2][lr] = v.z; Bs[4*q+3][lr] = v.w;
        }
        __syncthreads();
        #pragma unroll
        for (int kk = 0; kk < 16; ++kk) {
            float4 a = *(const float4*)&As[kk][ty * 4];
            float4 b = *(const float4*)&Bs[kk][tx * 4];
            float av[4] = {a.x, a.y, a.z, a.w};
            float bv[4] = {b.x, b.y, b.z, b.w};
            #pragma unroll
            for (int i = 0; i < 4; ++i)
                #pragma unroll
                for (int j = 0; j < 4; ++j)
                    acc[i][j] = fmaf(av[i], bv[j], acc[i][j]);
        }
        __syncthreads();
    }

    #pragma unroll
    for (int i = 0; i < 4; ++i) {
        const int gm = m0 + ty * 4 + i;
        if (gm >= M) continue;
        #pragma unroll
        for (int j = 0; j < 4; ++j) {
            const int gn = n0 + tx * 4 + j;
            if (gn >= N) continue;
            float v = acc[i][j] + bias[gn];
            if (ACT == 1)      v = lrelu_f(v);
            else if (ACT == 2) v = 1.f / (1.f + expf(-v));
            else if (ACT == 3) v = tanhf(lrelu_f(v));
            C[(size_t)gm * N + gn] = v;
        }
    }
}

// ---------------------------------------------------------------------------
// Row squared-norms (fp32 exact): sq[r] = sum_k X[r,k]^2
// ---------------------------------------------------------------------------
__global__ __launch_bounds__(256) void rowsq_kernel(
    const float* __restrict__ X, float* __restrict__ sq, int K)
{
    const int r = blockIdx.x;
    const int tid = threadIdx.x;
    float s = 0.f;
    const float* row = X + (size_t)r * K;
    for (int k = tid; k < K; k += 256) { float v = row[k]; s = fmaf(v, v, s); }
    __shared__ float red[256];
    red[tid] = s;
    __syncthreads();
    for (int off = 128; off > 0; off >>= 1) {
        if (tid < off) red[tid] += red[tid + off];
        __syncthreads();
    }
    if (tid == 0) sq[r] = red[0];
}

// ---------------------------------------------------------------------------
// fp32 -> bf16 hi/lo split, padded to SEG=800 per segment:
//   Xs[r][0:800]    = bf16_rn(x) (k<784, else 0)
//   Xs[r][800:1600] = bf16_rn(x - hi)
// ---------------------------------------------------------------------------
__global__ __launch_bounds__(256) void split_bf16_kernel(
    const float* __restrict__ X, short* __restrict__ Xs)
{
    const int idx = blockIdx.x * 256 + threadIdx.x;
    if (idx >= NB * SEG) return;
    const int r = idx / SEG, k = idx - r * SEG;
    short hi_s = 0, lo_s = 0;
    if (k < DIMX) {
        const float x = X[(size_t)r * DIMX + k];
        unsigned u = __float_as_uint(x);
        unsigned hib = (u + 0x7FFFu + ((u >> 16) & 1u)) & 0xFFFF0000u;  // RN to bf16
        const float hif = __uint_as_float(hib);
        const float lo = x - hif;                                      // exact in fp32
        unsigned ul = __float_as_uint(lo);
        unsigned lob = (ul + 0x7FFFu + ((ul >> 16) & 1u)) >> 16;
        hi_s = (short)(hib >> 16);
        lo_s = (short)lob;
    }
    Xs[(size_t)r * RS + k]       = hi_s;
    Xs[(size_t)r * RS + SEG + k] = lo_s;
}

// ---------------------------------------------------------------------------
// MFMA pdist: 3-term split Gram.
//   G = hi·h (seg0: A=hi,B=hi) + hi·l (seg1: A=hi,B=lo) + lo·h (seg2: A=lo,B=hi)
// 128x128 tile, BK=32, 4 waves (2x2), each wave 64x64 = 4x4 frags of 16x16x32.
// Upper-triangle tile grid only; epilogue: d = sqrt(max(sq_i + sq_j - 2G, 0)).
// ---------------------------------------------------------------------------
__global__ __launch_bounds__(256) void pdist_gram_mfma(
    const short* __restrict__ Xs, const float* __restrict__ sq,
    float* __restrict__ out)
{
    const int ti = blockIdx.y, tj = blockIdx.x;
    if (ti > tj) return;

    __shared__ short As[128 * 32];
    __shared__ short Bs[128 * 32];

    const int tid = threadIdx.x;
    const int w = tid >> 6, lane = tid & 63;
    const int wr = w >> 1, wc = w & 1;
    const int i0 = ti * 128, j0 = tj * 128;
    const int frow = lane & 15;          // row within 16x16 fragment
    const int fk   = (lane >> 4) * 8;    // k-offset within BK=32

    f32x4 acc[4][4] = {};

    // staging: thread -> (row tid>>2, 8-short chunk (tid&3)*8); dest linear per wave
    const int srow = tid >> 2;           // 0..63
    const int scol = (tid & 3) * 8;      // 0,8,16,24
    const short* gA = Xs + (size_t)(i0 + srow) * RS + scol;
    const short* gB = Xs + (size_t)(j0 + srow) * RS + scol;
    short* lA = As + w * 512;
    short* lB = Bs + w * 512;

    #pragma unroll 1
    for (int seg = 0; seg < 3; ++seg) {
        const int baseA = (seg == 2) ? SEG : 0;   // A: hi, hi, lo
        const int baseB = (seg == 1) ? SEG : 0;   // B: hi, lo, hi
        #pragma unroll 1
        for (int cc = 0; cc < 25; ++cc) {
            const int km = cc * 32;
            __syncthreads();             // previous iter's LDS reads done
            #pragma unroll
            for (int s = 0; s < 2; ++s) {
                __builtin_amdgcn_global_load_lds(
                    (const __attribute__((address_space(1))) void*)(gA + (size_t)s * 64 * RS + baseA + km),
                    (__attribute__((address_space(3))) void*)(lA + s * 2048), 16, 0, 0);
                __builtin_amdgcn_global_load_lds(
                    (const __attribute__((address_space(1))) void*)(gB + (size_t)s * 64 * RS + baseB + km),
                    (__attribute__((address_space(3))) void*)(lB + s * 2048), 16, 0, 0);
            }
            __syncthreads();             // barrier drains vmcnt

            bf16x8 a[4], b[4];
            #pragma unroll
            for (int m = 0; m < 4; ++m)
                a[m] = *(const bf16x8*)&As[(wr * 64 + m * 16 + frow) * 32 + fk];
            #pragma unroll
            for (int n = 0; n < 4; ++n)
                b[n] = *(const bf16x8*)&Bs[(wc * 64 + n * 16 + frow) * 32 + fk];
            #pragma unroll
            for (int m = 0; m < 4; ++m)
                #pragma unroll
                for (int n = 0; n < 4; ++n)
                    acc[m][n] = __builtin_amdgcn_mfma_f32_16x16x32_bf16(
                        a[m], b[n], acc[m][n], 0, 0, 0);
        }
    }

    // epilogue: C/D layout col = lane&15, row = (lane>>4)*4 + reg
    const int col0 = lane & 15;
    const int row4 = (lane >> 4) * 4;
    float sqj_v[4];
    #pragma unroll
    for (int n = 0; n < 4; ++n)
        sqj_v[n] = sq[j0 + wc * 64 + n * 16 + col0];

    #pragma unroll
    for (int m = 0; m < 4; ++m) {
        #pragma unroll
        for (int r = 0; r < 4; ++r) {
            const int gi = i0 + wr * 64 + m * 16 + row4 + r;
            const float sqi = sq[gi];
            const int rowbase = (gi * (2 * NB - 1 - gi)) / 2 - gi - 1;
            #pragma unroll
            for (int n = 0; n < 4; ++n) {
                const int gj = j0 + wc * 64 + n * 16 + col0;
                if (gj > gi) {
                    float d2 = sqi + sqj_v[n] - 2.f * acc[m][n][r];
                    out[rowbase + gj] = sqrtf(fmaxf(d2, 0.f));
                }
            }
        }
    }
}

// ---------------------------------------------------------------------------
// pdist for 2-D latent z, direct difference formula.
// ---------------------------------------------------------------------------
__global__ __launch_bounds__(256) void pdist_z(
    const float* __restrict__ Z, float* __restrict__ out)
{
    const int ti = blockIdx.y, tj = blockIdx.x;
    if (ti > tj) return;
    __shared__ float zi[64][2];
    __shared__ float zj[64][2];
    const int tid = threadIdx.x;
    if (tid < 128) {
        int r = tid >> 1, c = tid & 1;
        zi[r][c] = Z[(size_t)(ti * 64 + r) * 2 + c];
        zj[r][c] = Z[(size_t)(tj * 64 + r) * 2 + c];
    }
    __syncthreads();
    const int tx = tid & 15, ty = tid >> 4;
    #pragma unroll
    for (int i = 0; i < 4; ++i) {
        const int li = ty * 4 + i;
        const int gi = ti * 64 + li;
        #pragma unroll
        for (int j = 0; j < 4; ++j) {
            const int lj = tx * 4 + j;
            const int gj = tj * 64 + lj;
            if (gj > gi) {
                float d0 = zi[li][0] - zj[lj][0];
                float d1 = zi[li][1] - zj[lj][1];
                int idx = (gi * (2 * NB - 1 - gi)) / 2 + (gj - gi - 1);
                out[idx] = sqrtf(fmaf(d0, d0, d1 * d1));
            }
        }
    }
}

// ---------------------------------------------------------------------------
extern "C" void kernel_launch(void* const* d_in, const int* in_sizes, int n_in,
                              void* d_out, int out_size, void* d_ws, size_t ws_size,
                              hipStream_t stream)
{
    const float* x       = (const float*)d_in[0];
    const float* fc1_w   = (const float*)d_in[1];
    const float* fc1_b   = (const float*)d_in[2];
    const float* fc11_w  = (const float*)d_in[3];
    const float* fc11_b  = (const float*)d_in[4];
    const float* fc12_w  = (const float*)d_in[5];
    const float* fc12_b  = (const float*)d_in[6];
    const float* fc2_w   = (const float*)d_in[7];
    const float* fc2_b   = (const float*)d_in[8];
    const float* fc3_w   = (const float*)d_in[9];
    const float* fc3_b   = (const float*)d_in[10];
    const float* fc31_w  = (const float*)d_in[11];
    const float* fc31_b  = (const float*)d_in[12];
    const float* fc32_w  = (const float*)d_in[13];
    const float* fc32_b  = (const float*)d_in[14];
    const float* fc4_w   = (const float*)d_in[15];
    const float* fc4_b   = (const float*)d_in[16];

    float* out = (float*)d_out;
    const size_t Y_OFF   = 0;
    const size_t IN_OFF  = 3211264;
    const size_t LAT_OFF = 11597824;
    const size_t OUT_OFF = 19984384;
    const size_t Z_OFF   = 28370944;

    float* y        = out + Y_OFF;
    float* in_diff  = out + IN_OFF;
    float* lat_diff = out + LAT_OFF;
    float* out_diff = out + OUT_OFF;
    float* z        = out + Z_OFF;

    // workspace layout
    float* ws  = (float*)d_ws;
    float* h1  = ws;                      // 4096*400
    float* h2  = h1 + (size_t)4096 * 400; // 4096*200
    float* h3  = h2 + (size_t)4096 * 200; // 4096*50
    float* y1  = h3 + (size_t)4096 * 50;  // 4096*50
    float* y2  = y1 + (size_t)4096 * 50;  // 4096*200
    float* y3  = y2 + (size_t)4096 * 200; // 4096*400
    float* sqx = y3 + (size_t)4096 * 400; // 4096
    float* sqy = sqx + 4096;              // 4096
    short* xs  = (short*)(sqy + 4096);    // 4096*1600 shorts [hi|lo]
    short* ys  = xs + (size_t)NB * RS;    // 4096*1600 shorts [hi|lo]

    const dim3 blk(256);
    auto grd = [](int M, int N) { return dim3((N + 63) / 64, (M + 63) / 64); };
    const int splitBlocks = (NB * SEG + 255) / 256;

    // x-side prep (independent of MLP)
    split_bf16_kernel<<<dim3(splitBlocks), blk, 0, stream>>>(x, xs);
    rowsq_kernel<<<dim3(NB), blk, 0, stream>>>(x, sqx, DIMX);
    pdist_gram_mfma<<<dim3(32, 32), blk, 0, stream>>>(xs, sqx, in_diff);

    // encoder
    gemm_bias_act<1><<<grd(NB, 400), blk, 0, stream>>>(x,  fc1_w,  fc1_b,  h1, NB, 400, 784);
    gemm_bias_act<1><<<grd(NB, 200), blk, 0, stream>>>(h1, fc11_w, fc11_b, h2, NB, 200, 400);
    gemm_bias_act<3><<<grd(NB,  50), blk, 0, stream>>>(h2, fc12_w, fc12_b, h3, NB,  50, 200);
    gemm_bias_act<0><<<grd(NB,   2), blk, 0, stream>>>(h3, fc2_w,  fc2_b,  z,  NB,   2,  50);
    // decoder
    gemm_bias_act<1><<<grd(NB,  50), blk, 0, stream>>>(z,  fc3_w,  fc3_b,  y1, NB,  50,   2);
    gemm_bias_act<1><<<grd(NB, 200), blk, 0, stream>>>(y1, fc31_w, fc31_b, y2, NB, 200,  50);
    gemm_bias_act<1><<<grd(NB, 400), blk, 0, stream>>>(y2, fc32_w, fc32_b, y3, NB, 400, 200);
    gemm_bias_act<2><<<grd(NB, 784), blk, 0, stream>>>(y3, fc4_w,  fc4_b,  y,  NB, 784, 400);

    // y-side pdist
    split_bf16_kernel<<<dim3(splitBlocks), blk, 0, stream>>>(y, ys);
    rowsq_kernel<<<dim3(NB), blk, 0, stream>>>(y, sqy, DIMX);
    pdist_gram_mfma<<<dim3(32, 32), blk, 0, stream>>>(ys, sqy, out_diff);

    // latent pdist
    pdist_z<<<dim3(64, 64), blk, 0, stream>>>(z, lat_diff);
}

// Round 4
// 402.554 us; speedup vs baseline: 1.8938x; 1.3366x over previous
//
#include <hip/hip_runtime.h>
#include <math.h>

#define NB 4096            // batch
#define DIMX 784           // feature dim for x / y pdists
#define SEG 800            // padded K for x/y (25*32)
#define RSX 1600           // row stride in shorts for xs/ys: [hi(800)|lo(800)]

typedef __attribute__((ext_vector_type(8))) short bf16x8;
typedef __attribute__((ext_vector_type(4))) float f32x4;

__device__ __forceinline__ float lrelu_f(float v) { return v >= 0.f ? v : 0.01f * v; }

// round-to-nearest-even fp32 -> bf16 hi, exact residual -> bf16 lo
__device__ __forceinline__ void split1(float x, short& hi_s, short& lo_s) {
    unsigned u = __float_as_uint(x);
    unsigned hib = (u + 0x7FFFu + ((u >> 16) & 1u)) & 0xFFFF0000u;
    float hif = __uint_as_float(hib);
    float lo = x - hif;
    unsigned ul = __float_as_uint(lo);
    unsigned lob = (ul + 0x7FFFu + ((ul >> 16) & 1u)) >> 16;
    hi_s = (short)(hib >> 16);
    lo_s = (short)lob;
}

// ---------------------------------------------------------------------------
// fp32 [NB][K] -> split [NB][2*KP] (hi|lo), zero pad K..KP
// ---------------------------------------------------------------------------
__global__ __launch_bounds__(256) void split_act_kernel(
    const float* __restrict__ X, short* __restrict__ Xs, int K, int KP)
{
    const int idx = blockIdx.x * 256 + threadIdx.x;
    if (idx >= NB * KP) return;
    const int r = idx / KP, k = idx - r * KP;
    short hi = 0, lo = 0;
    if (k < K) split1(X[(size_t)r * K + k], hi, lo);
    Xs[(size_t)r * 2 * KP + k]      = hi;
    Xs[(size_t)r * 2 * KP + KP + k] = lo;
}

// fp32 W [N][K] -> split [NP][2*KP], zero pad rows/cols
__global__ __launch_bounds__(256) void split_w_kernel(
    const float* __restrict__ W, short* __restrict__ Ws, int N, int K, int NP, int KP)
{
    const int idx = blockIdx.x * 256 + threadIdx.x;
    if (idx >= NP * KP) return;
    const int r = idx / KP, k = idx - r * KP;
    short hi = 0, lo = 0;
    if (r < N && k < K) split1(W[(size_t)r * K + k], hi, lo);
    Ws[(size_t)r * 2 * KP + k]      = hi;
    Ws[(size_t)r * 2 * KP + KP + k] = lo;
}

// ---------------------------------------------------------------------------
// Row squared-norms (fp32 exact)
// ---------------------------------------------------------------------------
__global__ __launch_bounds__(256) void rowsq_kernel(
    const float* __restrict__ X, float* __restrict__ sq, int K)
{
    const int r = blockIdx.x;
    const int tid = threadIdx.x;
    float s = 0.f;
    const float* row = X + (size_t)r * K;
    for (int k = tid; k < K; k += 256) { float v = row[k]; s = fmaf(v, v, s); }
    __shared__ float red[256];
    red[tid] = s;
    __syncthreads();
    for (int off = 128; off > 0; off >>= 1) {
        if (tid < off) red[tid] += red[tid + off];
        __syncthreads();
    }
    if (tid == 0) sq[r] = red[0];
}

// ---------------------------------------------------------------------------
// Small fp32 GEMM (K or N tiny): C = act(A @ W^T + b). ACT: 0 none, 1 lrelu,
// 2 sigmoid, 3 tanh(lrelu)
// ---------------------------------------------------------------------------
template<int ACT>
__global__ __launch_bounds__(256) void gemm_bias_act(
    const float* __restrict__ A, const float* __restrict__ W,
    const float* __restrict__ bias, float* __restrict__ C,
    int M, int N, int K)
{
    __shared__ float As[16][64];
    __shared__ float Bs[16][64];
    const int tid = threadIdx.x;
    const int tx = tid & 15, ty = tid >> 4;
    const int m0 = blockIdx.y * 64, n0 = blockIdx.x * 64;
    const int q = tid & 3, lr = tid >> 2;

    float acc[4][4] = {};

    for (int kt = 0; kt < K; kt += 16) {
        const int gk = kt + 4 * q;
        {
            const int gm = m0 + lr;
            float4 v = {0.f, 0.f, 0.f, 0.f};
            if (gm < M) {
                if (((K & 3) == 0) && (gk + 3 < K)) {
                    v = *(const float4*)(A + (size_t)gm * K + gk);
                } else {
                    const float* p = A + (size_t)gm * K;
                    if (gk     < K) v.x = p[gk];
                    if (gk + 1 < K) v.y = p[gk + 1];
                    if (gk + 2 < K) v.z = p[gk + 2];
                    if (gk + 3 < K) v.w = p[gk + 3];
                }
            }
            As[4*q+0][lr] = v.x; As[4*q+1][lr] = v.y;
            As[4*q+2][lr] = v.z; As[4*q+3][lr] = v.w;
        }
        {
            const int gn = n0 + lr;
            float4 v = {0.f, 0.f, 0.f, 0.f};
            if (gn < N) {
                if (((K & 3) == 0) && (gk + 3 < K)) {
                    v = *(const float4*)(W + (size_t)gn * K + gk);
                } else {
                    const float* p = W + (size_t)gn * K;
                    if (gk     < K) v.x = p[gk];
                    if (gk + 1 < K) v.y = p[gk + 1];
                    if (gk + 2 < K) v.z = p[gk + 2];
                    if (gk + 3 < K) v.w = p[gk + 3];
                }
            }
            Bs[4*q+0][lr] = v.x; Bs[4*q+1][lr] = v.y;
            Bs[4*q+2][lr] = v.z; Bs[4*q+3][lr] = v.w;
        }
        __syncthreads();
        #pragma unroll
        for (int kk = 0; kk < 16; ++kk) {
            float4 a = *(const float4*)&As[kk][ty * 4];
            float4 b = *(const float4*)&Bs[kk][tx * 4];
            float av[4] = {a.x, a.y, a.z, a.w};
            float bv[4] = {b.x, b.y, b.z, b.w};
            #pragma unroll
            for (int i = 0; i < 4; ++i)
                #pragma unroll
                for (int j = 0; j < 4; ++j)
                    acc[i][j] = fmaf(av[i], bv[j], acc[i][j]);
        }
        __syncthreads();
    }

    #pragma unroll
    for (int i = 0; i < 4; ++i) {
        const int gm = m0 + ty * 4 + i;
        if (gm >= M) continue;
        #pragma unroll
        for (int j = 0; j < 4; ++j) {
            const int gn = n0 + tx * 4 + j;
            if (gn >= N) continue;
            float v = acc[i][j] + bias[gn];
            if (ACT == 1)      v = lrelu_f(v);
            else if (ACT == 2) v = 1.f / (1.f + expf(-v));
            else if (ACT == 3) v = tanhf(lrelu_f(v));
            C[(size_t)gm * N + gn] = v;
        }
    }
}

// ===========================================================================
// Shared MFMA core pieces: 128x128 tile, BK=32, 4 waves (2x2).
// Per K-chunk stage Ah/Al/Bh/Bl (32KB) into LDS[buf], 2-phase pipelined,
// then 48 MFMA: acc += Ah·Bh + Ah·Bl + Al·Bh (3-term bf16 split == ~fp32).
// ===========================================================================
#define GLL(srcp, dstp) __builtin_amdgcn_global_load_lds( \
    (const __attribute__((address_space(1))) void*)(srcp), \
    (__attribute__((address_space(3))) void*)(dstp), 16, 0, 0)

// ---------------------------------------------------------------------------
// bf16-split MFMA GEMM: C[M=NB][N] = act(A @ W^T + b)
// As_g: [NB][2*KP] shorts, Ws_g: [NP][2*KP] shorts (zero-padded rows)
// grid: (NP/128, NB/128)
// ---------------------------------------------------------------------------
template<int ACT>
__global__ __launch_bounds__(256) void gemm3_mfma(
    const short* __restrict__ As_g, const short* __restrict__ Ws_g,
    const float* __restrict__ bias, float* __restrict__ C,
    int N, int KP, int nchunk)
{
    __shared__ short L[2][4][4096];   // [buf][Ah,Al,Bh,Bl][128*32]
    const int tid = threadIdx.x;
    const int w = tid >> 6, lane = tid & 63;
    const int wr = w >> 1, wc = w & 1;
    const int m0 = blockIdx.y * 128, n0 = blockIdx.x * 128;
    const int frow = lane & 15, fk = (lane >> 4) * 8;
    const int srow = tid >> 2, scol = (tid & 3) * 8;
    const int RS = 2 * KP;
    const int ld0 = w * 512;          // + s*2048

    const short* gA0 = As_g + (size_t)(m0 + srow) * RS + scol;
    const short* gA1 = gA0 + (size_t)64 * RS;
    const short* gB0 = Ws_g + (size_t)(n0 + srow) * RS + scol;
    const short* gB1 = gB0 + (size_t)64 * RS;

    f32x4 acc[4][4] = {};

    auto stage = [&](int buf, int km) {
        GLL(gA0 + km,      &L[buf][0][ld0]);        GLL(gA1 + km,      &L[buf][0][ld0 + 2048]);
        GLL(gA0 + KP + km, &L[buf][1][ld0]);        GLL(gA1 + KP + km, &L[buf][1][ld0 + 2048]);
        GLL(gB0 + km,      &L[buf][2][ld0]);        GLL(gB1 + km,      &L[buf][2][ld0 + 2048]);
        GLL(gB0 + KP + km, &L[buf][3][ld0]);        GLL(gB1 + KP + km, &L[buf][3][ld0 + 2048]);
    };

    stage(0, 0);
    __syncthreads();
    int buf = 0;
    #pragma unroll 1
    for (int cc = 0; cc < nchunk; ++cc) {
        if (cc + 1 < nchunk) stage(buf ^ 1, (cc + 1) * 32);

        bf16x8 ah[4], al[4], bh[4], bl[4];
        #pragma unroll
        for (int m = 0; m < 4; ++m) {
            const int ro = (wr * 64 + m * 16 + frow) * 32 + fk;
            ah[m] = *(const bf16x8*)&L[buf][0][ro];
            al[m] = *(const bf16x8*)&L[buf][1][ro];
        }
        #pragma unroll
        for (int n = 0; n < 4; ++n) {
            const int ro = (wc * 64 + n * 16 + frow) * 32 + fk;
            bh[n] = *(const bf16x8*)&L[buf][2][ro];
            bl[n] = *(const bf16x8*)&L[buf][3][ro];
        }
        #pragma unroll
        for (int m = 0; m < 4; ++m)
            #pragma unroll
            for (int n = 0; n < 4; ++n) {
                acc[m][n] = __builtin_amdgcn_mfma_f32_16x16x32_bf16(ah[m], bh[n], acc[m][n], 0, 0, 0);
                acc[m][n] = __builtin_amdgcn_mfma_f32_16x16x32_bf16(ah[m], bl[n], acc[m][n], 0, 0, 0);
                acc[m][n] = __builtin_amdgcn_mfma_f32_16x16x32_bf16(al[m], bh[n], acc[m][n], 0, 0, 0);
            }
        __syncthreads();
        buf ^= 1;
    }

    // epilogue: C/D layout col = lane&15, row = (lane>>4)*4 + reg
    const int col0 = lane & 15;
    const int row4 = (lane >> 4) * 4;
    #pragma unroll
    for (int m = 0; m < 4; ++m) {
        #pragma unroll
        for (int r = 0; r < 4; ++r) {
            const int gm = m0 + wr * 64 + m * 16 + row4 + r;
            #pragma unroll
            for (int n = 0; n < 4; ++n) {
                const int gn = n0 + wc * 64 + n * 16 + col0;
                if (gn < N) {
                    float v = acc[m][n][r] + bias[gn];
                    if (ACT == 1)      v = lrelu_f(v);
                    else if (ACT == 2) v = 1.f / (1.f + expf(-v));
                    C[(size_t)gm * N + gn] = v;
                }
            }
        }
    }
}

// ---------------------------------------------------------------------------
// MFMA pdist (triangular grid, 528 blocks): G over split-bf16 (3-term),
// d = sqrt(max(sq_i + sq_j - 2G, 0)), pair-indexed output.
// ---------------------------------------------------------------------------
__global__ __launch_bounds__(256) void pdist_gram_mfma(
    const short* __restrict__ Xs, const float* __restrict__ sq,
    float* __restrict__ out)
{
    // linear bid -> upper-tri (ti, tj), ti <= tj, 32x32 tile grid
    int rem = blockIdx.x, ti = 0;
    while (rem >= 32 - ti) { rem -= 32 - ti; ++ti; }
    const int tj = ti + rem;

    __shared__ short L[2][4][4096];   // [buf][Ah,Al,Bh,Bl][128*32]
    const int tid = threadIdx.x;
    const int w = tid >> 6, lane = tid & 63;
    const int wr = w >> 1, wc = w & 1;
    const int i0 = ti * 128, j0 = tj * 128;
    const int frow = lane & 15, fk = (lane >> 4) * 8;
    const int srow = tid >> 2, scol = (tid & 3) * 8;
    const int ld0 = w * 512;

    const short* gA0 = Xs + (size_t)(i0 + srow) * RSX + scol;
    const short* gA1 = gA0 + (size_t)64 * RSX;
    const short* gB0 = Xs + (size_t)(j0 + srow) * RSX + scol;
    const short* gB1 = gB0 + (size_t)64 * RSX;

    f32x4 acc[4][4] = {};

    auto stage = [&](int buf, int km) {
        GLL(gA0 + km,       &L[buf][0][ld0]);       GLL(gA1 + km,       &L[buf][0][ld0 + 2048]);
        GLL(gA0 + SEG + km, &L[buf][1][ld0]);       GLL(gA1 + SEG + km, &L[buf][1][ld0 + 2048]);
        GLL(gB0 + km,       &L[buf][2][ld0]);       GLL(gB1 + km,       &L[buf][2][ld0 + 2048]);
        GLL(gB0 + SEG + km, &L[buf][3][ld0]);       GLL(gB1 + SEG + km, &L[buf][3][ld0 + 2048]);
    };

    stage(0, 0);
    __syncthreads();
    int buf = 0;
    #pragma unroll 1
    for (int cc = 0; cc < 25; ++cc) {
        if (cc + 1 < 25) stage(buf ^ 1, (cc + 1) * 32);

        bf16x8 ah[4], al[4], bh[4], bl[4];
        #pragma unroll
        for (int m = 0; m < 4; ++m) {
            const int ro = (wr * 64 + m * 16 + frow) * 32 + fk;
            ah[m] = *(const bf16x8*)&L[buf][0][ro];
            al[m] = *(const bf16x8*)&L[buf][1][ro];
        }
        #pragma unroll
        for (int n = 0; n < 4; ++n) {
            const int ro = (wc * 64 + n * 16 + frow) * 32 + fk;
            bh[n] = *(const bf16x8*)&L[buf][2][ro];
            bl[n] = *(const bf16x8*)&L[buf][3][ro];
        }
        #pragma unroll
        for (int m = 0; m < 4; ++m)
            #pragma unroll
            for (int n = 0; n < 4; ++n) {
                acc[m][n] = __builtin_amdgcn_mfma_f32_16x16x32_bf16(ah[m], bh[n], acc[m][n], 0, 0, 0);
                acc[m][n] = __builtin_amdgcn_mfma_f32_16x16x32_bf16(ah[m], bl[n], acc[m][n], 0, 0, 0);
                acc[m][n] = __builtin_amdgcn_mfma_f32_16x16x32_bf16(al[m], bh[n], acc[m][n], 0, 0, 0);
            }
        __syncthreads();
        buf ^= 1;
    }

    const int col0 = lane & 15;
    const int row4 = (lane >> 4) * 4;
    float sqj_v[4];
    #pragma unroll
    for (int n = 0; n < 4; ++n)
        sqj_v[n] = sq[j0 + wc * 64 + n * 16 + col0];

    #pragma unroll
    for (int m = 0; m < 4; ++m) {
        #pragma unroll
        for (int r = 0; r < 4; ++r) {
            const int gi = i0 + wr * 64 + m * 16 + row4 + r;
            const float sqi = sq[gi];
            const int rowbase = (gi * (2 * NB - 1 - gi)) / 2 - gi - 1;
            #pragma unroll
            for (int n = 0; n < 4; ++n) {
                const int gj = j0 + wc * 64 + n * 16 + col0;
                if (gj > gi) {
                    float d2 = sqi + sqj_v[n] - 2.f * acc[m][n][r];
                    out[rowbase + gj] = sqrtf(fmaxf(d2, 0.f));
                }
            }
        }
    }
}

// ---------------------------------------------------------------------------
// pdist for 2-D latent z, direct difference formula.
// ---------------------------------------------------------------------------
__global__ __launch_bounds__(256) void pdist_z(
    const float* __restrict__ Z, float* __restrict__ out)
{
    const int ti = blockIdx.y, tj = blockIdx.x;
    if (ti > tj) return;
    __shared__ float zi[64][2];
    __shared__ float zj[64][2];
    const int tid = threadIdx.x;
    if (tid < 128) {
        int r = tid >> 1, c = tid & 1;
        zi[r][c] = Z[(size_t)(ti * 64 + r) * 2 + c];
        zj[r][c] = Z[(size_t)(tj * 64 + r) * 2 + c];
    }
    __syncthreads();
    const int tx = tid & 15, ty = tid >> 4;
    #pragma unroll
    for (int i = 0; i < 4; ++i) {
        const int li = ty * 4 + i;
        const int gi = ti * 64 + li;
        #pragma unroll
        for (int j = 0; j < 4; ++j) {
            const int lj = tx * 4 + j;
            const int gj = tj * 64 + lj;
            if (gj > gi) {
                float d0 = zi[li][0] - zj[lj][0];
                float d1 = zi[li][1] - zj[lj][1];
                int idx = (gi * (2 * NB - 1 - gi)) / 2 + (gj - gi - 1);
                out[idx] = sqrtf(fmaf(d0, d0, d1 * d1));
            }
        }
    }
}

// ---------------------------------------------------------------------------
extern "C" void kernel_launch(void* const* d_in, const int* in_sizes, int n_in,
                              void* d_out, int out_size, void* d_ws, size_t ws_size,
                              hipStream_t stream)
{
    const float* x       = (const float*)d_in[0];
    const float* fc1_w   = (const float*)d_in[1];
    const float* fc1_b   = (const float*)d_in[2];
    const float* fc11_w  = (const float*)d_in[3];
    const float* fc11_b  = (const float*)d_in[4];
    const float* fc12_w  = (const float*)d_in[5];
    const float* fc12_b  = (const float*)d_in[6];
    const float* fc2_w   = (const float*)d_in[7];
    const float* fc2_b   = (const float*)d_in[8];
    const float* fc3_w   = (const float*)d_in[9];
    const float* fc3_b   = (const float*)d_in[10];
    const float* fc31_w  = (const float*)d_in[11];
    const float* fc31_b  = (const float*)d_in[12];
    const float* fc32_w  = (const float*)d_in[13];
    const float* fc32_b  = (const float*)d_in[14];
    const float* fc4_w   = (const float*)d_in[15];
    const float* fc4_b   = (const float*)d_in[16];

    float* out = (float*)d_out;
    float* y        = out;                 // 4096*784
    float* in_diff  = out + 3211264;       // 8386560
    float* lat_diff = out + 11597824;      // 8386560
    float* out_diff = out + 19984384;      // 8386560
    float* z        = out + 28370944;      // 4096*2

    // ---- workspace layout (proven footprint ~47.5 MB, with aliasing) ----
    float* ws  = (float*)d_ws;
    float* h1  = ws;                        // 4096*400 f32
    float* h2  = h1 + (size_t)4096 * 400;   // 4096*200
    float* h3  = h2 + (size_t)4096 * 200;   // 4096*50
    float* y1  = h3 + (size_t)4096 * 50;    // 4096*50
    float* y2  = y1 + (size_t)4096 * 50;    // 4096*200
    float* y3  = y2 + (size_t)4096 * 200;   // 4096*400
    float* sqx = y3 + (size_t)4096 * 400;   // 4096
    float* sqy = sqx + 4096;                // 4096
    short* xs  = (short*)(sqy + 4096);      // 4096*1600 shorts (13.1 MB)
    short* ys  = xs + (size_t)NB * RSX;     // 4096*1600 shorts (13.1 MB)

    // aliases inside xs region (xs dead after fc1):
    short* h1s = xs;                        // 4096*832  (6.8 MB)  [after fc1]
    short* y2s = xs + (size_t)4096 * 832;   // 4096*448  (3.7 MB)  [after fc31]
    short* y3s = xs;                        // 4096*832  (reuse h1s; h1s dead after fc11)
    // aliases inside ys region (all dead before split_y writes ys):
    short* w1s  = ys;                         // 512*1600
    short* w11s = w1s  + (size_t)512 * 1600;  // 256*832
    short* w32s = w11s + (size_t)256 * 832;   // 512*448
    short* w4s  = w32s + (size_t)512 * 448;   // 896*832

    const dim3 blk(256);
    auto grd64 = [](int M, int N) { return dim3((N + 63) / 64, (M + 63) / 64); };
    auto spl   = [](int tot) { return dim3((tot + 255) / 256); };

    // ---- weight splits (independent, run first; live in ys region) ----
    split_w_kernel<<<spl(512 * 800), blk, 0, stream>>>(fc1_w,  w1s,  400, 784, 512, 800);
    split_w_kernel<<<spl(256 * 416), blk, 0, stream>>>(fc11_w, w11s, 200, 400, 256, 416);
    split_w_kernel<<<spl(512 * 224), blk, 0, stream>>>(fc32_w, w32s, 400, 200, 512, 224);
    split_w_kernel<<<spl(896 * 416), blk, 0, stream>>>(fc4_w,  w4s,  784, 400, 896, 416);

    // ---- x side: split, norms, pdist ----
    split_act_kernel<<<spl(NB * 800), blk, 0, stream>>>(x, xs, 784, 800);
    rowsq_kernel<<<dim3(NB), blk, 0, stream>>>(x, sqx, DIMX);
    pdist_gram_mfma<<<dim3(528), blk, 0, stream>>>(xs, sqx, in_diff);

    // ---- encoder ----
    gemm3_mfma<1><<<dim3(4, 32), blk, 0, stream>>>(xs,  w1s,  fc1_b,  h1, 400, 800, 25);
    split_act_kernel<<<spl(NB * 416), blk, 0, stream>>>(h1, h1s, 400, 416);   // overwrites xs
    gemm3_mfma<1><<<dim3(2, 32), blk, 0, stream>>>(h1s, w11s, fc11_b, h2, 200, 416, 13);
    gemm_bias_act<3><<<grd64(NB, 50), blk, 0, stream>>>(h2, fc12_w, fc12_b, h3, NB, 50, 200);
    gemm_bias_act<0><<<grd64(NB,  2), blk, 0, stream>>>(h3, fc2_w,  fc2_b,  z,  NB,  2,  50);

    // ---- decoder ----
    gemm_bias_act<1><<<grd64(NB, 50),  blk, 0, stream>>>(z,  fc3_w,  fc3_b,  y1, NB, 50,  2);
    gemm_bias_act<1><<<grd64(NB, 200), blk, 0, stream>>>(y1, fc31_w, fc31_b, y2, NB, 200, 50);
    split_act_kernel<<<spl(NB * 224), blk, 0, stream>>>(y2, y2s, 200, 224);
    gemm3_mfma<1><<<dim3(4, 32), blk, 0, stream>>>(y2s, w32s, fc32_b, y3, 400, 224, 7);
    split_act_kernel<<<spl(NB * 416), blk, 0, stream>>>(y3, y3s, 400, 416);   // reuses h1s region
    gemm3_mfma<2><<<dim3(7, 32), blk, 0, stream>>>(y3s, w4s, fc4_b, y, 784, 416, 13);

    // ---- y side: split, norms, pdist ----
    split_act_kernel<<<spl(NB * 800), blk, 0, stream>>>(y, ys, 784, 800);     // w*s dead now
    rowsq_kernel<<<dim3(NB), blk, 0, stream>>>(y, sqy, DIMX);
    pdist_gram_mfma<<<dim3(528), blk, 0, stream>>>(ys, sqy, out_diff);

    // ---- latent pdist ----
    pdist_z<<<dim3(64, 64), blk, 0, stream>>>(z, lat_diff);
}

// Round 6
// 369.240 us; speedup vs baseline: 2.0647x; 1.0902x over previous
//
#include <hip/hip_runtime.h>
#include <math.h>

#define NB 4096            // batch
#define DIMX 784           // feature dim for x / y pdists

typedef __attribute__((ext_vector_type(8))) short bf16x8;
typedef __attribute__((ext_vector_type(4))) float f32x4;

__device__ __forceinline__ float lrelu_f(float v) { return v >= 0.f ? v : 0.01f * v; }

// round-to-nearest-even fp32 -> bf16 hi, residual -> bf16 lo
__device__ __forceinline__ void split1(float x, short& hi_s, short& lo_s) {
    unsigned u = __float_as_uint(x);
    unsigned hib = (u + 0x7FFFu + ((u >> 16) & 1u)) & 0xFFFF0000u;
    float hif = __uint_as_float(hib);
    float lo = x - hif;
    unsigned ul = __float_as_uint(lo);
    unsigned lob = (ul + 0x7FFFu + ((ul >> 16) & 1u)) >> 16;
    hi_s = (short)(hib >> 16);
    lo_s = (short)lob;
}

#define GLL(srcp, dstp) __builtin_amdgcn_global_load_lds( \
    (const __attribute__((address_space(1))) void*)(srcp), \
    (__attribute__((address_space(3))) void*)(dstp), 16, 0, 0)

// ---------------------------------------------------------------------------
// fp32 [NB][K] -> split [NB][2*KP] (hi|lo), zero pad K..KP  (used for x only)
// ---------------------------------------------------------------------------
__global__ __launch_bounds__(256) void split_act_kernel(
    const float* __restrict__ X, short* __restrict__ Xs, int K, int KP)
{
    const int idx = blockIdx.x * 256 + threadIdx.x;
    if (idx >= NB * KP) return;
    const int r = idx / KP, k = idx - r * KP;
    short hi = 0, lo = 0;
    if (k < K) split1(X[(size_t)r * K + k], hi, lo);
    Xs[(size_t)r * 2 * KP + k]      = hi;
    Xs[(size_t)r * 2 * KP + KP + k] = lo;
}

// fp32 W [N][K] -> split [NP][2*KP], zero pad rows/cols
__global__ __launch_bounds__(256) void split_w_kernel(
    const float* __restrict__ W, short* __restrict__ Ws, int N, int K, int NP, int KP)
{
    const int idx = blockIdx.x * 256 + threadIdx.x;
    if (idx >= NP * KP) return;
    const int r = idx / KP, k = idx - r * KP;
    short hi = 0, lo = 0;
    if (r < N && k < K) split1(W[(size_t)r * K + k], hi, lo);
    Ws[(size_t)r * 2 * KP + k]      = hi;
    Ws[(size_t)r * 2 * KP + KP + k] = lo;
}

// ---------------------------------------------------------------------------
// Row squared-norms (fp32 exact)
// ---------------------------------------------------------------------------
__global__ __launch_bounds__(256) void rowsq_kernel(
    const float* __restrict__ X, float* __restrict__ sq, int K)
{
    const int r = blockIdx.x;
    const int tid = threadIdx.x;
    float s = 0.f;
    const float* row = X + (size_t)r * K;
    for (int k = tid; k < K; k += 256) { float v = row[k]; s = fmaf(v, v, s); }
    __shared__ float red[256];
    red[tid] = s;
    __syncthreads();
    for (int off = 128; off > 0; off >>= 1) {
        if (tid < off) red[tid] += red[tid + off];
        __syncthreads();
    }
    if (tid == 0) sq[r] = red[0];
}

// ---------------------------------------------------------------------------
// Small fp32 GEMM: C = act(A @ W^T + b). SPLIT: write bf16 hi/lo [M][2*KPo]
// instead of f32 (zero beyond N). ACT: 0 none, 1 lrelu, 2 sigmoid, 3 tanh(lrelu)
// ---------------------------------------------------------------------------
template<int ACT, bool SPLIT>
__global__ __launch_bounds__(256) void gemm_small(
    const float* __restrict__ A, const float* __restrict__ W,
    const float* __restrict__ bias, float* __restrict__ C,
    short* __restrict__ Cs, int M, int N, int K, int KPo)
{
    __shared__ float As[16][64];
    __shared__ float Bs[16][64];
    const int tid = threadIdx.x;
    const int tx = tid & 15, ty = tid >> 4;
    const int m0 = blockIdx.y * 64, n0 = blockIdx.x * 64;
    const int q = tid & 3, lr = tid >> 2;

    float acc[4][4] = {};

    for (int kt = 0; kt < K; kt += 16) {
        const int gk = kt + 4 * q;
        {
            const int gm = m0 + lr;
            float4 v = {0.f, 0.f, 0.f, 0.f};
            if (gm < M) {
                if (((K & 3) == 0) && (gk + 3 < K)) {
                    v = *(const float4*)(A + (size_t)gm * K + gk);
                } else {
                    const float* p = A + (size_t)gm * K;
                    if (gk     < K) v.x = p[gk];
                    if (gk + 1 < K) v.y = p[gk + 1];
                    if (gk + 2 < K) v.z = p[gk + 2];
                    if (gk + 3 < K) v.w = p[gk + 3];
                }
            }
            As[4*q+0][lr] = v.x; As[4*q+1][lr] = v.y;
            As[4*q+2][lr] = v.z; As[4*q+3][lr] = v.w;
        }
        {
            const int gn = n0 + lr;
            float4 v = {0.f, 0.f, 0.f, 0.f};
            if (gn < N) {
                if (((K & 3) == 0) && (gk + 3 < K)) {
                    v = *(const float4*)(W + (size_t)gn * K + gk);
                } else {
                    const float* p = W + (size_t)gn * K;
                    if (gk     < K) v.x = p[gk];
                    if (gk + 1 < K) v.y = p[gk + 1];
                    if (gk + 2 < K) v.z = p[gk + 2];
                    if (gk + 3 < K) v.w = p[gk + 3];
                }
            }
            Bs[4*q+0][lr] = v.x; Bs[4*q+1][lr] = v.y;
            Bs[4*q+2][lr] = v.z; Bs[4*q+3][lr] = v.w;
        }
        __syncthreads();
        #pragma unroll
        for (int kk = 0; kk < 16; ++kk) {
            float4 a = *(const float4*)&As[kk][ty * 4];
            float4 b = *(const float4*)&Bs[kk][tx * 4];
            float av[4] = {a.x, a.y, a.z, a.w};
            float bv[4] = {b.x, b.y, b.z, b.w};
            #pragma unroll
            for (int i = 0; i < 4; ++i)
                #pragma unroll
                for (int j = 0; j < 4; ++j)
                    acc[i][j] = fmaf(av[i], bv[j], acc[i][j]);
        }
        __syncthreads();
    }

    #pragma unroll
    for (int i = 0; i < 4; ++i) {
        const int gm = m0 + ty * 4 + i;
        if (gm >= M) continue;
        #pragma unroll
        for (int j = 0; j < 4; ++j) {
            const int gn = n0 + tx * 4 + j;
            float v = 0.f;
            if (gn < N) {
                v = acc[i][j] + bias[gn];
                if (ACT == 1)      v = lrelu_f(v);
                else if (ACT == 2) v = 1.f / (1.f + expf(-v));
                else if (ACT == 3) v = tanhf(lrelu_f(v));
            }
            if (SPLIT) {
                if (gn < KPo) {
                    short hi, lo; split1(v, hi, lo);
                    Cs[(size_t)gm * 2 * KPo + gn]       = hi;
                    Cs[(size_t)gm * 2 * KPo + KPo + gn] = lo;
                }
            } else {
                if (gn < N) C[(size_t)gm * N + gn] = v;
            }
        }
    }
}

// ---------------------------------------------------------------------------
// bf16-split MFMA GEMM, 3-TERM (hh + hl + lh): out = act(A @ W^T + b)
// A:[NB][2*KPi] (hi|lo), W:[NP][2*KPi]. 128x128 tile, BK=32, 4 waves,
// 2-phase pipelined, Ah/Al/Bh/Bl staged per chunk.
// Epilogue: optional f32 C [M][N], optional split Cs [M][2*KPo] (zeros gn>=N).
// ---------------------------------------------------------------------------
template<int ACT, bool WF32, bool WSPLIT>
__global__ __launch_bounds__(256) void gemm3_mfma(
    const short* __restrict__ As_g, const short* __restrict__ Ws_g,
    const float* __restrict__ bias, float* __restrict__ C,
    short* __restrict__ Cs, int N, int KPi, int nchunk, int KPo)
{
    __shared__ short L[2][4][4096];   // [buf][Ah,Al,Bh,Bl][128*32]
    const int tid = threadIdx.x;
    const int w = tid >> 6, lane = tid & 63;
    const int wr = w >> 1, wc = w & 1;
    const int m0 = blockIdx.y * 128, n0 = blockIdx.x * 128;
    const int frow = lane & 15, fk = (lane >> 4) * 8;
    const int srow = tid >> 2, scol = (tid & 3) * 8;
    const int RS = 2 * KPi;
    const int ld0 = w * 512;

    const short* gA0 = As_g + (size_t)(m0 + srow) * RS + scol;
    const short* gA1 = gA0 + (size_t)64 * RS;
    const short* gB0 = Ws_g + (size_t)(n0 + srow) * RS + scol;
    const short* gB1 = gB0 + (size_t)64 * RS;

    f32x4 acc[4][4] = {};

    auto stage = [&](int buf, int km) {
        GLL(gA0 + km,       &L[buf][0][ld0]);     GLL(gA1 + km,       &L[buf][0][ld0 + 2048]);
        GLL(gA0 + KPi + km, &L[buf][1][ld0]);     GLL(gA1 + KPi + km, &L[buf][1][ld0 + 2048]);
        GLL(gB0 + km,       &L[buf][2][ld0]);     GLL(gB1 + km,       &L[buf][2][ld0 + 2048]);
        GLL(gB0 + KPi + km, &L[buf][3][ld0]);     GLL(gB1 + KPi + km, &L[buf][3][ld0 + 2048]);
    };

    stage(0, 0);
    __syncthreads();
    int buf = 0;
    #pragma unroll 1
    for (int cc = 0; cc < nchunk; ++cc) {
        if (cc + 1 < nchunk) stage(buf ^ 1, (cc + 1) * 32);

        bf16x8 ah[4], al[4], bh[4], bl[4];
        #pragma unroll
        for (int m = 0; m < 4; ++m) {
            const int ro = (wr * 64 + m * 16 + frow) * 32 + fk;
            ah[m] = *(const bf16x8*)&L[buf][0][ro];
            al[m] = *(const bf16x8*)&L[buf][1][ro];
        }
        #pragma unroll
        for (int n = 0; n < 4; ++n) {
            const int ro = (wc * 64 + n * 16 + frow) * 32 + fk;
            bh[n] = *(const bf16x8*)&L[buf][2][ro];
            bl[n] = *(const bf16x8*)&L[buf][3][ro];
        }
        #pragma unroll
        for (int m = 0; m < 4; ++m)
            #pragma unroll
            for (int n = 0; n < 4; ++n) {
                acc[m][n] = __builtin_amdgcn_mfma_f32_16x16x32_bf16(ah[m], bh[n], acc[m][n], 0, 0, 0);
                acc[m][n] = __builtin_amdgcn_mfma_f32_16x16x32_bf16(ah[m], bl[n], acc[m][n], 0, 0, 0);
                acc[m][n] = __builtin_amdgcn_mfma_f32_16x16x32_bf16(al[m], bh[n], acc[m][n], 0, 0, 0);
            }
        __syncthreads();
        buf ^= 1;
    }

    const int col0 = lane & 15;
    const int row4 = (lane >> 4) * 4;
    #pragma unroll
    for (int m = 0; m < 4; ++m) {
        #pragma unroll
        for (int r = 0; r < 4; ++r) {
            const int gm = m0 + wr * 64 + m * 16 + row4 + r;
            #pragma unroll
            for (int n = 0; n < 4; ++n) {
                const int gn = n0 + wc * 64 + n * 16 + col0;
                float v = 0.f;
                if (gn < N) {
                    v = acc[m][n][r] + bias[gn];
                    if (ACT == 1)      v = lrelu_f(v);
                    else if (ACT == 2) v = 1.f / (1.f + expf(-v));
                }
                if (WF32 && gn < N) C[(size_t)gm * N + gn] = v;
                if (WSPLIT && gn < KPo) {
                    short hi, lo; split1(v, hi, lo);
                    Cs[(size_t)gm * 2 * KPo + gn]       = hi;
                    Cs[(size_t)gm * 2 * KPo + KPo + gn] = lo;
                }
            }
        }
    }
}

// ---------------------------------------------------------------------------
// Merged MFMA pdist for x and y, 3-TERM split math (hh + hl + lh).
// 272 blocks = 2 x 136 triangular 256-tiles. 256x256 tile, KP=800, BK=32,
// 512 threads (8 waves 2x4, each 128x64), Ah/Al/Bh/Bl double-buffered
// (128 KiB LDS), 2-phase pipeline, bijective XCD swizzle (272 = 8*34).
// ---------------------------------------------------------------------------
__global__ __launch_bounds__(512, 2) void pdist_dual(
    const short* __restrict__ xs, const short* __restrict__ ys,
    const float* __restrict__ sqx, const float* __restrict__ sqy,
    float* __restrict__ in_diff, float* __restrict__ out_diff)
{
    const int orig = blockIdx.x;
    const int wg = (orig & 7) * 34 + (orig >> 3);

    const short* Xs; const float* sq; float* out; int b;
    if (wg < 136) { Xs = xs; sq = sqx; out = in_diff;  b = wg; }
    else          { Xs = ys; sq = sqy; out = out_diff; b = wg - 136; }
    int rem = b, ti = 0;
    while (rem >= 16 - ti) { rem -= 16 - ti; ++ti; }
    const int tj = ti + rem;

    __shared__ short L[2][4][8192];   // [buf][Ah,Al,Bh,Bl][256*32] = 128 KiB
    const int tid = threadIdx.x;
    const int w = tid >> 6, lane = tid & 63;
    const int wr = w >> 2, wc = w & 3;        // 2x4 waves, wave tile 128x64
    const int i0 = ti * 256, j0 = tj * 256;
    const int frow = lane & 15, fk = (lane >> 4) * 8;
    const int srow = w * 16 + (lane >> 2), scol = (lane & 3) * 8;
    const int ld0 = w * 512;

    const short* gA = Xs + (size_t)(i0 + srow) * 1600 + scol;
    const short* gB = Xs + (size_t)(j0 + srow) * 1600 + scol;
    const size_t half = (size_t)128 * 1600;

    f32x4 acc[8][4] = {};

    auto stage = [&](int buf, int km) {
        GLL(gA + km,              &L[buf][0][ld0]);   GLL(gA + half + km,       &L[buf][0][4096 + ld0]);
        GLL(gA + 800 + km,        &L[buf][1][ld0]);   GLL(gA + half + 800 + km, &L[buf][1][4096 + ld0]);
        GLL(gB + km,              &L[buf][2][ld0]);   GLL(gB + half + km,       &L[buf][2][4096 + ld0]);
        GLL(gB + 800 + km,        &L[buf][3][ld0]);   GLL(gB + half + 800 + km, &L[buf][3][4096 + ld0]);
    };

    stage(0, 0);
    __syncthreads();
    int buf = 0;
    #pragma unroll 1
    for (int cc = 0; cc < 25; ++cc) {
        if (cc + 1 < 25) stage(buf ^ 1, (cc + 1) * 32);

        bf16x8 ah[8], bh[4];
        #pragma unroll
        for (int m = 0; m < 8; ++m)
            ah[m] = *(const bf16x8*)&L[buf][0][(wr * 128 + m * 16 + frow) * 32 + fk];
        #pragma unroll
        for (int n = 0; n < 4; ++n)
            bh[n] = *(const bf16x8*)&L[buf][2][(wc * 64 + n * 16 + frow) * 32 + fk];
        #pragma unroll
        for (int m = 0; m < 8; ++m)
            #pragma unroll
            for (int n = 0; n < 4; ++n)
                acc[m][n] = __builtin_amdgcn_mfma_f32_16x16x32_bf16(ah[m], bh[n], acc[m][n], 0, 0, 0);

        {   // term 2: ah x bl
            bf16x8 bl[4];
            #pragma unroll
            for (int n = 0; n < 4; ++n)
                bl[n] = *(const bf16x8*)&L[buf][3][(wc * 64 + n * 16 + frow) * 32 + fk];
            #pragma unroll
            for (int m = 0; m < 8; ++m)
                #pragma unroll
                for (int n = 0; n < 4; ++n)
                    acc[m][n] = __builtin_amdgcn_mfma_f32_16x16x32_bf16(ah[m], bl[n], acc[m][n], 0, 0, 0);
        }
        {   // term 3: al x bh
            bf16x8 al[8];
            #pragma unroll
            for (int m = 0; m < 8; ++m)
                al[m] = *(const bf16x8*)&L[buf][1][(wr * 128 + m * 16 + frow) * 32 + fk];
            #pragma unroll
            for (int m = 0; m < 8; ++m)
                #pragma unroll
                for (int n = 0; n < 4; ++n)
                    acc[m][n] = __builtin_amdgcn_mfma_f32_16x16x32_bf16(al[m], bh[n], acc[m][n], 0, 0, 0);
        }
        __syncthreads();
        buf ^= 1;
    }

    // epilogue: C/D layout col = lane&15, row = (lane>>4)*4 + reg
    const int col0 = lane & 15;
    const int row4 = (lane >> 4) * 4;
    float sqj_v[4];
    #pragma unroll
    for (int n = 0; n < 4; ++n)
        sqj_v[n] = sq[j0 + wc * 64 + n * 16 + col0];

    #pragma unroll
    for (int m = 0; m < 8; ++m) {
        #pragma unroll
        for (int r = 0; r < 4; ++r) {
            const int gi = i0 + wr * 128 + m * 16 + row4 + r;
            const float sqi = sq[gi];
            const int rowbase = (gi * (2 * NB - 1 - gi)) / 2 - gi - 1;
            #pragma unroll
            for (int n = 0; n < 4; ++n) {
                const int gj = j0 + wc * 64 + n * 16 + col0;
                if (gj > gi) {
                    float d2 = sqi + sqj_v[n] - 2.f * acc[m][n][r];
                    out[rowbase + gj] = sqrtf(fmaxf(d2, 0.f));
                }
            }
        }
    }
}

// ---------------------------------------------------------------------------
// pdist for 2-D latent z, triangular grid (64x64 pair-tiles, 2080 blocks)
// ---------------------------------------------------------------------------
__global__ __launch_bounds__(256) void pdist_z(
    const float* __restrict__ Z, float* __restrict__ out)
{
    int rem = blockIdx.x, ti = 0;
    while (rem >= 64 - ti) { rem -= 64 - ti; ++ti; }
    const int tj = ti + rem;

    __shared__ float zi[64][2];
    __shared__ float zj[64][2];
    const int tid = threadIdx.x;
    if (tid < 128) {
        int r = tid >> 1, c = tid & 1;
        zi[r][c] = Z[(size_t)(ti * 64 + r) * 2 + c];
        zj[r][c] = Z[(size_t)(tj * 64 + r) * 2 + c];
    }
    __syncthreads();
    const int tx = tid & 15, ty = tid >> 4;
    #pragma unroll
    for (int i = 0; i < 4; ++i) {
        const int li = ty * 4 + i;
        const int gi = ti * 64 + li;
        #pragma unroll
        for (int j = 0; j < 4; ++j) {
            const int lj = tx * 4 + j;
            const int gj = tj * 64 + lj;
            if (gj > gi) {
                float d0 = zi[li][0] - zj[lj][0];
                float d1 = zi[li][1] - zj[lj][1];
                int idx = (gi * (2 * NB - 1 - gi)) / 2 + (gj - gi - 1);
                out[idx] = sqrtf(fmaf(d0, d0, d1 * d1));
            }
        }
    }
}

// ---------------------------------------------------------------------------
extern "C" void kernel_launch(void* const* d_in, const int* in_sizes, int n_in,
                              void* d_out, int out_size, void* d_ws, size_t ws_size,
                              hipStream_t stream)
{
    const float* x       = (const float*)d_in[0];
    const float* fc1_w   = (const float*)d_in[1];
    const float* fc1_b   = (const float*)d_in[2];
    const float* fc11_w  = (const float*)d_in[3];
    const float* fc11_b  = (const float*)d_in[4];
    const float* fc12_w  = (const float*)d_in[5];
    const float* fc12_b  = (const float*)d_in[6];
    const float* fc2_w   = (const float*)d_in[7];
    const float* fc2_b   = (const float*)d_in[8];
    const float* fc3_w   = (const float*)d_in[9];
    const float* fc3_b   = (const float*)d_in[10];
    const float* fc31_w  = (const float*)d_in[11];
    const float* fc31_b  = (const float*)d_in[12];
    const float* fc32_w  = (const float*)d_in[13];
    const float* fc32_b  = (const float*)d_in[14];
    const float* fc4_w   = (const float*)d_in[15];
    const float* fc4_b   = (const float*)d_in[16];

    float* out = (float*)d_out;
    float* y        = out;                 // 4096*784
    float* in_diff  = out + 3211264;       // 8386560
    float* lat_diff = out + 11597824;      // 8386560
    float* out_diff = out + 19984384;      // 8386560
    float* z        = out + 28370944;      // 4096*2

    // ---- workspace layout (all disjoint except y3s aliases h1s) ----
    float* ws   = (float*)d_ws;
    float* h2   = ws;                          // 4096*200 f32
    float* h3   = h2  + (size_t)4096 * 200;    // 4096*50
    float* y1   = h3  + (size_t)4096 * 50;     // 4096*50
    float* sqx  = y1  + (size_t)4096 * 50;     // 4096
    float* sqy  = sqx + 4096;                  // 4096
    short* xs   = (short*)(sqy + 4096);        // 4096*1600 (13.1 MB)
    short* ys   = xs  + (size_t)NB * 1600;     // 4096*1600 (13.1 MB)
    short* w1s  = ys  + (size_t)NB * 1600;     // 512*1600
    short* w11s = w1s  + (size_t)512 * 1600;   // 256*832
    short* w32s = w11s + (size_t)256 * 832;    // 512*448
    short* w4s  = w32s + (size_t)512 * 448;    // 896*832
    short* h1s  = w4s  + (size_t)896 * 832;    // 4096*832 (6.8 MB)
    short* y3s  = h1s;                         // alias: h1s dead after fc11
    short* y2s  = h1s  + (size_t)4096 * 832;   // 4096*448 (3.7 MB)

    const dim3 blk(256);
    auto spl = [](int tot) { return dim3((tot + 255) / 256); };

    // ---- weight splits (independent) ----
    split_w_kernel<<<spl(512 * 800), blk, 0, stream>>>(fc1_w,  w1s,  400, 784, 512, 800);
    split_w_kernel<<<spl(256 * 416), blk, 0, stream>>>(fc11_w, w11s, 200, 400, 256, 416);
    split_w_kernel<<<spl(512 * 224), blk, 0, stream>>>(fc32_w, w32s, 400, 200, 512, 224);
    split_w_kernel<<<spl(896 * 416), blk, 0, stream>>>(fc4_w,  w4s,  784, 400, 896, 416);

    // ---- x prep ----
    split_act_kernel<<<spl(NB * 800), blk, 0, stream>>>(x, xs, 784, 800);
    rowsq_kernel<<<dim3(NB), blk, 0, stream>>>(x, sqx, DIMX);

    // ---- encoder ----
    gemm3_mfma<1, false, true><<<dim3(4, 32), blk, 0, stream>>>(
        xs, w1s, fc1_b, nullptr, h1s, 400, 800, 25, 416);
    gemm3_mfma<1, true, false><<<dim3(2, 32), blk, 0, stream>>>(
        h1s, w11s, fc11_b, h2, nullptr, 200, 416, 13, 0);
    gemm_small<3, false><<<dim3(1, 64), blk, 0, stream>>>(
        h2, fc12_w, fc12_b, h3, nullptr, NB, 50, 200, 0);
    gemm_small<0, false><<<dim3(1, 64), blk, 0, stream>>>(
        h3, fc2_w, fc2_b, z, nullptr, NB, 2, 50, 0);

    // ---- decoder ----
    gemm_small<1, false><<<dim3(1, 64), blk, 0, stream>>>(
        z, fc3_w, fc3_b, y1, nullptr, NB, 50, 2, 0);
    gemm_small<1, true><<<dim3(4, 64), blk, 0, stream>>>(
        y1, fc31_w, fc31_b, nullptr, y2s, NB, 200, 50, 224);
    gemm3_mfma<1, false, true><<<dim3(4, 32), blk, 0, stream>>>(
        y2s, w32s, fc32_b, nullptr, y3s, 400, 224, 7, 416);
    gemm3_mfma<2, true, true><<<dim3(7, 32), blk, 0, stream>>>(
        y3s, w4s, fc4_b, y, ys, 784, 416, 13, 800);

    // ---- y norms, merged pdists ----
    rowsq_kernel<<<dim3(NB), blk, 0, stream>>>(y, sqy, DIMX);
    pdist_dual<<<dim3(272), dim3(512), 0, stream>>>(xs, ys, sqx, sqy, in_diff, out_diff);

    // ---- latent pdist ----
    pdist_z<<<dim3(2080), blk, 0, stream>>>(z, lat_diff);
}